// Round 8
// baseline (708.931 us; speedup 1.0000x reference)
//
#include <hip/hip_runtime.h>
#include <hip/hip_bf16.h>

#define HID   128
#define OUTD  64
#define NPROD 100000
#define NCUST 50000
#define EPP   800000
#define EPC   800000
#define ELB   400000
#define BCAP  2048
#define RCAP  256      // per-replica capacity (2x headroom over ~128 mean)
#define CPAD  800      // counter stride (buckets) per replica bank

typedef __bf16 bf16x8 __attribute__((ext_vector_type(8)));
typedef float  f32x4  __attribute__((ext_vector_type(4)));
typedef unsigned short u16;
typedef unsigned int u32;

__device__ __forceinline__ float b2f(u16 u) {
  unsigned int v = ((unsigned int)u) << 16;
  float f; __builtin_memcpy(&f, &v, 4); return f;
}
__device__ __forceinline__ u16 f2b(float f) {
  __hip_bfloat16 h = __float2bfloat16(f);
  u16 u; __builtin_memcpy(&u, &h, 2); return u;
}

union Pack8 { u16 u[8]; int4 v; };

// XOR-swizzled LDS index for 128-col rows (16B chunks, swizzle by row&15).
__device__ __forceinline__ int sidx(int row, int chunk) {
  return row * HID + ((chunk ^ (row & 15)) << 3);
}
// Same for 64-col rows (8 chunks, swizzle by row&7).
__device__ __forceinline__ int sidx64(int row, int chunk) {
  return row * 64 + ((chunk ^ (row & 7)) << 3);
}

// ---------------- fp32 -> bf16 cast (8 elems/thread) ----------------
__global__ __launch_bounds__(256) void k_cast(const float* __restrict__ src,
                                              u16* __restrict__ dst, int n8) {
  int i = blockIdx.x * 256 + threadIdx.x;
  if (i >= n8) return;
  float4 a = ((const float4*)src)[2 * i];
  float4 b = ((const float4*)src)[2 * i + 1];
  Pack8 p;
  p.u[0] = f2b(a.x); p.u[1] = f2b(a.y); p.u[2] = f2b(a.z); p.u[3] = f2b(a.w);
  p.u[4] = f2b(b.x); p.u[5] = f2b(b.y); p.u[6] = f2b(b.z); p.u[7] = f2b(b.w);
  ((int4*)dst)[i] = p.v;
}

#define NJOBS 13
struct CastJobs { const float* src[NJOBS]; int n8[NJOBS]; };

__global__ __launch_bounds__(256) void k_cast_w(CastJobs jobs, u16* __restrict__ wbuf) {
  int job = blockIdx.x >> 3;
  int idx = (blockIdx.x & 7) * 256 + threadIdx.x;
  int off8 = (job < 10) ? job * 2048 : 10 * 2048 + (job - 10) * 1024;
  if (idx >= jobs.n8[job]) return;
  const float* s = jobs.src[job];
  float4 a = ((const float4*)s)[2 * idx];
  float4 b = ((const float4*)s)[2 * idx + 1];
  Pack8 p;
  p.u[0] = f2b(a.x); p.u[1] = f2b(a.y); p.u[2] = f2b(a.z); p.u[3] = f2b(a.w);
  p.u[4] = f2b(b.x); p.u[5] = f2b(b.y); p.u[6] = f2b(b.z); p.u[7] = f2b(b.w);
  ((int4*)wbuf)[off8 + idx] = p.v;
}

// ---------------- CSR build: combined bucket scatter, XCD-replicated ----------
// Counters one-per-64B-line (atomics serialize per line); replica = real XCC id
// so each XCD's counter+data lines stay in its own L2. Both graphs in one
// launch (first half of blocks = pp, second = pc) for 2x atomic line spread.
__global__ __launch_bounds__(256) void k_bucket2(const int* __restrict__ ei_pp,
                                                 const int* __restrict__ ei_pc,
                                                 int* __restrict__ bfill_pp,
                                                 int* __restrict__ bfill_pc,
                                                 u32* __restrict__ bss_pp,
                                                 u32* __restrict__ bss_pc) {
  int gb = blockIdx.x;
  int xcc;
  asm("s_getreg_b32 %0, hwreg(HW_REG_XCC_ID)" : "=s"(xcc));
  int rep = xcc & 7;
  if (gb < EPP / 256) {
    int e = gb * 256 + threadIdx.x;
    int d = ei_pp[EPP + e];
    int b = d >> 7;
    int p = atomicAdd(&bfill_pp[(rep * CPAD + b) << 4], 1);
    if (p < RCAP)
      bss_pp[(b << 11) + (rep << 8) + p] = ((u32)ei_pp[e] << 7) | (u32)(d & 127);
  } else {
    int e = (gb - EPP / 256) * 256 + threadIdx.x;
    int d = ei_pc[EPC + e];
    int b = d >> 6;
    int p = atomicAdd(&bfill_pc[(rep * CPAD + b) << 4], 1);
    if (p < RCAP)
      bss_pc[(b << 11) + (rep << 8) + p] = ((u32)ei_pc[e] << 7) | (u32)(d & 127);
  }
}

// Pass B: one block per bucket; LDS counting sort; coalesced CSR writes.
template <int K>
__global__ __launch_bounds__(256) void k_bsort(const u32* __restrict__ bss,
                                               const int* __restrict__ bfill,
                                               int* __restrict__ gctr,
                                               int* __restrict__ esrc,
                                               int* __restrict__ start,
                                               int* __restrict__ cnt,
                                               int n_nodes) {
  __shared__ u32 pairs[BCAP];
  __shared__ int outsrc[BCAP];
  __shared__ int lcnt[K], lstart[K], lfill[K];
  __shared__ int sh_n, sh_base, rn[8], roff[8];
  const int b = blockIdx.x, tid = threadIdx.x;
  if (tid < 8) rn[tid] = min(bfill[(tid * CPAD + b) << 4], RCAP);
  for (int j = tid; j < K; j += 256) { lcnt[j] = 0; lfill[j] = 0; }
  __syncthreads();
  if (tid == 0) {
    int run = 0;
    for (int r = 0; r < 8; ++r) { roff[r] = run; run += rn[r]; }
    sh_n = run;
    sh_base = atomicAdd(gctr, run);
  }
  __syncthreads();
  const int n = sh_n, base = sh_base;
  #pragma unroll
  for (int r = 0; r < 8; ++r) {
    int m = rn[r], o = roff[r];
    for (int i = tid; i < m; i += 256) {
      u32 p = bss[(b << 11) + (r << 8) + i];
      pairs[o + i] = p;
      atomicAdd(&lcnt[p & (K - 1)], 1);
    }
  }
  __syncthreads();
  if (tid == 0) {
    int run = 0;
    for (int j = 0; j < K; ++j) { lstart[j] = run; run += lcnt[j]; }
  }
  __syncthreads();
  for (int i = tid; i < n; i += 256) {
    u32 p = pairs[i];
    int ln = p & (K - 1);
    int pos = lstart[ln] + atomicAdd(&lfill[ln], 1);
    outsrc[pos] = (int)(p >> 7);
  }
  __syncthreads();
  for (int i = tid; i < n; i += 256) esrc[base + i] = outsrc[i];
  const int nb0 = b * K;
  for (int j = tid; j < K; j += 256) {
    int g = nb0 + j;
    if (g < n_nodes) { start[g] = base + lstart[j]; cnt[g] = lcnt[j]; }
  }
}

// ---------------- standalone mean aggregation (quarter-wave per node) --------
__global__ __launch_bounds__(256) void k_agg(const int* __restrict__ esrc,
                                             const int* __restrict__ start,
                                             const int* __restrict__ cnt,
                                             const u16* __restrict__ x,
                                             u16* __restrict__ outm, int n_dst) {
  int node = blockIdx.x * 16 + (threadIdx.x >> 4);
  int l16  = threadIdx.x & 15;
  if (node >= n_dst) return;
  int s0 = start[node], c = cnt[node];
  float acc[8] = {0.f, 0.f, 0.f, 0.f, 0.f, 0.f, 0.f, 0.f};
  for (int j0 = 0; j0 < c; j0 += 16) {
    int nch = min(16, c - j0);
    int eid = (l16 < nch) ? esrc[s0 + j0 + l16] : 0;
    for (int k = 0; k < nch; ++k) {
      int s = __shfl(eid, (threadIdx.x & 48) + k, 64);
      Pack8 p;
      p.v = *(const int4*)(x + (size_t)s * HID + l16 * 8);
      #pragma unroll
      for (int t = 0; t < 8; ++t) acc[t] += b2f(p.u[t]);
    }
  }
  float inv = 1.0f / (float)max(c, 1);
  Pack8 o;
  #pragma unroll
  for (int t = 0; t < 8; ++t) o.u[t] = f2b(acc[t] * inv);
  *(int4*)(outm + (size_t)node * HID + l16 * 8) = o.v;
}

// ---------------- fused (dual-K) GEMM with optional in-kernel aggregation ----
// out = act( phase0 @ W1^T + A2 @ W2^T + bias ), phase0 = A1 rows (AGG=false)
// or CSR-mean of X rows (AGG=true, gathered straight into LDS).
template <int BN, bool DUAL, bool RELU, bool A2F, bool AGG>
__global__ __launch_bounds__(256) void k_gemm(const u16* __restrict__ A1,
                                              const u16* __restrict__ W1,
                                              const void* __restrict__ A2v,
                                              const u16* __restrict__ W2,
                                              const float* __restrict__ bias,
                                              u16* __restrict__ out, int M,
                                              const int* __restrict__ esrc,
                                              const int* __restrict__ start,
                                              const int* __restrict__ cnt,
                                              const u16* __restrict__ X) {
  __shared__ __align__(16) u16 sA[64 * HID];
  __shared__ __align__(16) u16 sW[BN * HID];
  const int tid  = threadIdx.x;
  const int lane = tid & 63;
  const int wave = tid >> 6;
  const int q    = lane >> 4;
  const int r16  = lane & 15;
  const int m0   = blockIdx.x * 64;
  constexpr int NT = BN / 64;

  f32x4 acc[4][NT];
  #pragma unroll
  for (int i = 0; i < 4; ++i)
    #pragma unroll
    for (int j = 0; j < NT; ++j) {
      acc[i][j][0] = 0.f; acc[i][j][1] = 0.f; acc[i][j][2] = 0.f; acc[i][j][3] = 0.f;
    }

  #pragma unroll
  for (int phase = 0; phase < (DUAL ? 2 : 1); ++phase) {
    const u16* W = phase ? W2 : W1;
    if (phase) __syncthreads();
    if (phase == 0 && AGG) {
      // gather-aggregate 64 nodes directly into sA (quarter-wave per node)
      const int l16 = tid & 15;
      #pragma unroll
      for (int p = 0; p < 4; ++p) {
        int rr = p * 16 + (tid >> 4);
        int node = m0 + rr;
        Pack8 o; o.v = make_int4(0, 0, 0, 0);
        if (node < M) {
          int s0 = start[node], c = cnt[node];
          float a8[8] = {0.f, 0.f, 0.f, 0.f, 0.f, 0.f, 0.f, 0.f};
          for (int j0 = 0; j0 < c; j0 += 16) {
            int nch = min(16, c - j0);
            int eid = (l16 < nch) ? esrc[s0 + j0 + l16] : 0;
            for (int k = 0; k < nch; ++k) {
              int s = __shfl(eid, (tid & 48) + k, 64);
              Pack8 px;
              px.v = *(const int4*)(X + (size_t)s * HID + l16 * 8);
              #pragma unroll
              for (int t = 0; t < 8; ++t) a8[t] += b2f(px.u[t]);
            }
          }
          float inv = 1.0f / (float)max(c, 1);
          #pragma unroll
          for (int t = 0; t < 8; ++t) o.u[t] = f2b(a8[t] * inv);
        }
        *(int4*)(sA + sidx(rr, l16)) = o.v;
      }
    } else {
      #pragma unroll
      for (int i = 0; i < 4; ++i) {
        int idx = i * 256 + tid;
        int rr = idx >> 4, c8 = idx & 15;
        int gr = m0 + rr;
        Pack8 p; p.v = make_int4(0, 0, 0, 0);
        if (gr < M) {
          if (phase == 0 || !A2F) {
            const u16* A = phase ? (const u16*)A2v : A1;
            p.v = *(const int4*)(A + (size_t)gr * HID + c8 * 8);
          } else {
            const float* A = (const float*)A2v;
            const float* s = A + (size_t)gr * HID + c8 * 8;
            float4 f0 = ((const float4*)s)[0], f1 = ((const float4*)s)[1];
            p.u[0] = f2b(f0.x); p.u[1] = f2b(f0.y); p.u[2] = f2b(f0.z); p.u[3] = f2b(f0.w);
            p.u[4] = f2b(f1.x); p.u[5] = f2b(f1.y); p.u[6] = f2b(f1.z); p.u[7] = f2b(f1.w);
          }
        }
        *(int4*)(sA + sidx(rr, c8)) = p.v;
      }
    }
    #pragma unroll
    for (int i = 0; i < BN / 16; ++i) {
      int idx = i * 256 + tid;
      int rr = idx >> 4, c8 = idx & 15;
      *(int4*)(sW + sidx(rr, c8)) = *(const int4*)(W + (size_t)rr * HID + c8 * 8);
    }
    __syncthreads();
    #pragma unroll
    for (int ks = 0; ks < 4; ++ks) {
      int chunk = ks * 4 + q;
      bf16x8 a[4], b[NT];
      #pragma unroll
      for (int mi = 0; mi < 4; ++mi)
        a[mi] = *(const bf16x8*)(sA + sidx(mi * 16 + r16, chunk));
      #pragma unroll
      for (int ni = 0; ni < NT; ++ni)
        b[ni] = *(const bf16x8*)(sW + sidx(wave * (16 * NT) + ni * 16 + r16, chunk));
      #pragma unroll
      for (int mi = 0; mi < 4; ++mi)
        #pragma unroll
        for (int ni = 0; ni < NT; ++ni)
          acc[mi][ni] = __builtin_amdgcn_mfma_f32_16x16x32_bf16(a[mi], b[ni], acc[mi][ni], 0, 0, 0);
    }
  }
  #pragma unroll
  for (int ni = 0; ni < NT; ++ni) {
    int col = wave * (16 * NT) + ni * 16 + r16;
    float bv = bias[col];
    #pragma unroll
    for (int mi = 0; mi < 4; ++mi) {
      #pragma unroll
      for (int r = 0; r < 4; ++r) {
        int gr = m0 + mi * 16 + q * 4 + r;
        if (gr < M) {
          float v = acc[mi][ni][r] + bv;
          if (RELU) v = fmaxf(v, 0.f);
          out[(size_t)gr * BN + col] = f2b(v);
        }
      }
    }
  }
}

// ---------------- K=64 GEMM: out[M,64] = A[M,64] @ Wsub^T (+bias) -------------
// Wsub = 64x64 slice of a [64,128] row-major matrix (row stride 128).
template <bool HASB>
__global__ __launch_bounds__(256) void k_gemm64(const u16* __restrict__ A,
                                                const u16* __restrict__ W,
                                                const float* __restrict__ bias,
                                                u16* __restrict__ out, int M) {
  __shared__ __align__(16) u16 sA[64 * 64];
  __shared__ __align__(16) u16 sW[64 * 64];
  const int tid  = threadIdx.x;
  const int lane = tid & 63;
  const int wave = tid >> 6;
  const int q    = lane >> 4;
  const int r16  = lane & 15;
  const int m0   = blockIdx.x * 64;
  // stage A (64x64): 512 int4 / 256 threads = 2 iters
  #pragma unroll
  for (int i = 0; i < 2; ++i) {
    int idx = i * 256 + tid;
    int rr = idx >> 3, c8 = idx & 7;
    int gr = m0 + rr;
    int4 v = make_int4(0, 0, 0, 0);
    if (gr < M) v = *(const int4*)(A + (size_t)gr * 64 + c8 * 8);
    *(int4*)(sA + sidx64(rr, c8)) = v;
  }
  // stage W (64 rows x 64 cols, row stride 128)
  #pragma unroll
  for (int i = 0; i < 2; ++i) {
    int idx = i * 256 + tid;
    int rr = idx >> 3, c8 = idx & 7;
    *(int4*)(sW + sidx64(rr, c8)) = *(const int4*)(W + (size_t)rr * HID + c8 * 8);
  }
  __syncthreads();
  f32x4 acc[4];
  #pragma unroll
  for (int i = 0; i < 4; ++i) { acc[i][0]=0.f; acc[i][1]=0.f; acc[i][2]=0.f; acc[i][3]=0.f; }
  #pragma unroll
  for (int ks = 0; ks < 2; ++ks) {
    int chunk = ks * 4 + q;
    bf16x8 b = *(const bf16x8*)(sW + sidx64(wave * 16 + r16, chunk));
    #pragma unroll
    for (int mi = 0; mi < 4; ++mi) {
      bf16x8 a = *(const bf16x8*)(sA + sidx64(mi * 16 + r16, chunk));
      acc[mi] = __builtin_amdgcn_mfma_f32_16x16x32_bf16(a, b, acc[mi], 0, 0, 0);
    }
  }
  int col = wave * 16 + r16;
  float bv = HASB ? bias[col] : 0.f;
  #pragma unroll
  for (int mi = 0; mi < 4; ++mi)
    #pragma unroll
    for (int r = 0; r < 4; ++r) {
      int gr = m0 + mi * 16 + q * 4 + r;
      if (gr < M) out[(size_t)gr * 64 + col] = f2b(acc[mi][r] + bv);
    }
}

// ---------------- edge scorer: out[e] = w2 . relu(U[row]+V[col]) + b2 ---------
// 8 lanes per edge, one dwordx4 from U and V each; shfl-reduce the dot.
__global__ __launch_bounds__(256) void k_edge(const u16* __restrict__ U,
                                              const u16* __restrict__ V,
                                              const int* __restrict__ eli,
                                              const float* __restrict__ w2,
                                              const float* __restrict__ b2,
                                              float* __restrict__ out) {
  const int tid  = threadIdx.x;
  const int lane = tid & 63;
  const int wave = tid >> 6;
  const int se   = (lane >> 3);      // sub-edge in wave (0..7)
  const int ch   = lane & 7;         // 16B chunk (0..7)
  float w2c[8];
  #pragma unroll
  for (int j = 0; j < 8; ++j) w2c[j] = w2[ch * 8 + j];
  const float b2v = b2[0];
  const int e0 = blockIdx.x * 256;
  #pragma unroll
  for (int p = 0; p < 8; ++p) {
    int e = e0 + p * 32 + wave * 8 + se;
    if (e < ELB) {
      int r = eli[e];
      int c = eli[ELB + e];
      Pack8 pu, pv;
      pu.v = *(const int4*)(U + (size_t)r * 64 + ch * 8);
      pv.v = *(const int4*)(V + (size_t)c * 64 + ch * 8);
      float s = 0.f;
      #pragma unroll
      for (int j = 0; j < 8; ++j)
        s += fmaxf(b2f(pu.u[j]) + b2f(pv.u[j]), 0.f) * w2c[j];
      s += __shfl_xor(s, 1, 64);
      s += __shfl_xor(s, 2, 64);
      s += __shfl_xor(s, 4, 64);
      if (ch == 0) out[e] = s + b2v;
    }
  }
}

extern "C" void kernel_launch(void* const* d_in, const int* in_sizes, int n_in,
                              void* d_out, int out_size, void* d_ws, size_t ws_size,
                              hipStream_t stream) {
  const float* x_prod = (const float*)d_in[0];
  const float* x_cust = (const float*)d_in[1];
  const int* ei_pp    = (const int*)d_in[2];
  const int* ei_pc    = (const int*)d_in[3];
  const int* eli      = (const int*)d_in[4];

  const float *it_W1l, *it_W1r, *it_b1, *it_W2l, *it_W2r, *it_b2, *it_Wlin, *it_blin;
  const float *us_W1l, *us_W1r, *us_b1, *us_W2l, *us_W2r, *us_b2;
  const float *us_W3l, *us_W3r, *us_b3, *us_Wlin, *us_blin;
  if (in_sizes[6] == 128) {   // signature order (Wl, b, Wr)
    it_W1l  = (const float*)d_in[5];  it_b1   = (const float*)d_in[6];  it_W1r  = (const float*)d_in[7];
    it_W2l  = (const float*)d_in[8];  it_b2   = (const float*)d_in[9];  it_W2r  = (const float*)d_in[10];
    it_Wlin = (const float*)d_in[11]; it_blin = (const float*)d_in[12];
    us_W1l  = (const float*)d_in[13]; us_b1   = (const float*)d_in[14]; us_W1r  = (const float*)d_in[15];
    us_W2l  = (const float*)d_in[16]; us_b2   = (const float*)d_in[17]; us_W2r  = (const float*)d_in[18];
    us_W3l  = (const float*)d_in[19]; us_b3   = (const float*)d_in[20]; us_W3r  = (const float*)d_in[21];
    us_Wlin = (const float*)d_in[22]; us_blin = (const float*)d_in[23];
  } else {                    // setup_inputs dict order (Wl, Wr, b)
    it_W1l  = (const float*)d_in[5];  it_W1r  = (const float*)d_in[6];  it_b1   = (const float*)d_in[7];
    it_W2l  = (const float*)d_in[8];  it_W2r  = (const float*)d_in[9];  it_b2   = (const float*)d_in[10];
    it_Wlin = (const float*)d_in[11]; it_blin = (const float*)d_in[12];
    us_W1l  = (const float*)d_in[13]; us_W1r  = (const float*)d_in[14]; us_b1   = (const float*)d_in[15];
    us_W2l  = (const float*)d_in[16]; us_W2r  = (const float*)d_in[17]; us_b2   = (const float*)d_in[18];
    us_W3l  = (const float*)d_in[19]; us_W3r  = (const float*)d_in[20]; us_b3   = (const float*)d_in[21];
    us_Wlin = (const float*)d_in[22]; us_blin = (const float*)d_in[23];
  }
  const float* de_W1 = (const float*)d_in[24];
  const float* de_b1 = (const float*)d_in[25];
  const float* de_W2 = (const float*)d_in[26];
  const float* de_b2 = (const float*)d_in[27];

  const int NB_PP = (NPROD + 127) / 128;   // 782
  const int NB_PC = (NCUST + 63) / 64;     // 782

  char* ws = (char*)d_ws;
  int* bfill_pp = (int*)(ws + 0);              // 409600 B (line-padded)
  int* bfill_pc = (int*)(ws + 409600);         // 409600 B
  int* gctr     = (int*)(ws + 819200);         // 8 B (memset 0..819208)
  int* start_pp = (int*)(ws + 819264);
  int* cnt_pp   = (int*)(ws + 1219264);
  int* start_pc = (int*)(ws + 1619264);
  int* cnt_pc   = (int*)(ws + 1819264);
  int* esrc_pp  = (int*)(ws + 2019264);        // 3.2 MB
  int* esrc_pc  = (int*)(ws + 5219264);        // 3.2 MB
  u16* wbuf  = (u16*)(ws + 8419264);           // 376832 B
  u16* XPB   = (u16*)(ws + 8796096);           // 25.6 MB: bf16 x_prod -> PX -> V
  u16* meanb = (u16*)(ws + 34396096);          // 25.6 MB: mean_pp1 -> p2
  u16* P1    = (u16*)(ws + 59996096);          // 25.6 MB: bss -> p1 -> ZP
  u16* ZC    = (u16*)(ws + 85596096);          // 6.4 MB
  u16* U     = (u16*)(ws + 91996096);          // 6.4 MB
  u16* CX    = (u16*)(ws + 98396096);          // 12.8 MB -> peak ~111.2 MB
  u32* bss_pp = (u32*)P1;                      // 6.4 MB
  u32* bss_pc = (u32*)(ws + 59996096 + 6553600);
  u16* PX = XPB;
  u16* ZP = P1;
  u16* V  = XPB;

  u16* w_it1l = wbuf + 0 * 16384;  u16* w_it1r = wbuf + 1 * 16384;
  u16* w_it2l = wbuf + 2 * 16384;  u16* w_it2r = wbuf + 3 * 16384;
  u16* w_us1l = wbuf + 4 * 16384;  u16* w_us1r = wbuf + 5 * 16384;
  u16* w_us2l = wbuf + 6 * 16384;  u16* w_us2r = wbuf + 7 * 16384;
  u16* w_us3l = wbuf + 8 * 16384;  u16* w_us3r = wbuf + 9 * 16384;
  u16* w_itlin = wbuf + 10 * 16384;
  u16* w_uslin = wbuf + 10 * 16384 + 8192;
  u16* w_deW1  = wbuf + 10 * 16384 + 2 * 8192;

  (void)n_in; (void)out_size; (void)ws_size;

  hipMemsetAsync(d_ws, 0, 819208, stream);

  dim3 B(256);
  k_cast<<<dim3((NPROD * HID / 8 + 255) / 256), B, 0, stream>>>(x_prod, XPB, NPROD * HID / 8);
  CastJobs jobs;
  jobs.src[0] = it_W1l;  jobs.src[1] = it_W1r;  jobs.src[2] = it_W2l;  jobs.src[3] = it_W2r;
  jobs.src[4] = us_W1l;  jobs.src[5] = us_W1r;  jobs.src[6] = us_W2l;  jobs.src[7] = us_W2r;
  jobs.src[8] = us_W3l;  jobs.src[9] = us_W3r;
  jobs.src[10] = it_Wlin; jobs.src[11] = us_Wlin; jobs.src[12] = de_W1;
  for (int i = 0; i < 10; ++i) jobs.n8[i] = 2048;
  for (int i = 10; i < 13; ++i) jobs.n8[i] = 1024;
  k_cast_w<<<dim3(NJOBS * 8), B, 0, stream>>>(jobs, wbuf);

  // CSR build (both graphs in one bucket pass)
  k_bucket2<<<dim3(EPP / 256 + EPC / 256), B, 0, stream>>>(ei_pp, ei_pc, bfill_pp, bfill_pc,
                                                           bss_pp, bss_pc);
  k_bsort<128><<<dim3(NB_PP), B, 0, stream>>>(bss_pp, bfill_pp, gctr, esrc_pp, start_pp, cnt_pp, NPROD);
  k_bsort<64><<<dim3(NB_PC), B, 0, stream>>>(bss_pc, bfill_pc, gctr + 1, esrc_pc, start_pc, cnt_pc, NCUST);

  dim3 Gp((NPROD + 63) / 64), Gc((NCUST + 63) / 64);

  // mean_pp1 (consumed twice -> standalone)
  k_agg<<<dim3((NPROD + 15) / 16), B, 0, stream>>>(esrc_pp, start_pp, cnt_pp, XPB, meanb, NPROD);
  // cx = relu(mean_pc(XPB)@W2l + x_cust@W2r + b2)  [fused agg; must precede PX overwrite]
  k_gemm<128, true, true, true, true><<<Gc, B, 0, stream>>>(
      nullptr, w_us2l, x_cust, w_us2r, us_b2, CX, NCUST, esrc_pc, start_pc, cnt_pc, XPB);
  // p1 / px from shared mean_pp1
  k_gemm<128, true, true, false, false><<<Gp, B, 0, stream>>>(
      meanb, w_it1l, XPB, w_it1r, it_b1, P1, NPROD, nullptr, nullptr, nullptr, nullptr);
  k_gemm<128, true, true, false, false><<<Gp, B, 0, stream>>>(
      meanb, w_us1l, XPB, w_us1r, us_b1, PX, NPROD, nullptr, nullptr, nullptr, nullptr);
  // p2 = relu(mean_pp(P1)@W2l + P1@W2r + b2)  [fused agg; out meanb (dead), src P1 intact]
  k_gemm<128, true, true, false, true><<<Gp, B, 0, stream>>>(
      nullptr, w_it2l, P1, w_it2r, it_b2, meanb, NPROD, esrc_pp, start_pp, cnt_pp, P1);
  // z_prod = p2 @ it_Wlin^T  -> ZP (over dead P1)
  k_gemm<64, false, false, false, false><<<Gp, B, 0, stream>>>(
      meanb, w_itlin, nullptr, nullptr, it_blin, ZP, NPROD, nullptr, nullptr, nullptr, nullptr);
  // cx2 = relu(mean_pc(PX)@W3l + CX@W3r + b3)  [fused agg; in-place over CX]
  k_gemm<128, true, true, false, true><<<Gc, B, 0, stream>>>(
      nullptr, w_us3l, CX, w_us3r, us_b3, CX, NCUST, esrc_pc, start_pc, cnt_pc, PX);
  // z_cust = cx2 @ us_Wlin^T -> ZC
  k_gemm<64, false, false, false, false><<<Gc, B, 0, stream>>>(
      CX, w_uslin, nullptr, nullptr, us_blin, ZC, NCUST, nullptr, nullptr, nullptr, nullptr);
  // decoder pre-transforms: U = ZC@W1c^T + b1 ; V = ZP@W1p^T (over dead XPB/PX)
  k_gemm64<true><<<Gc, B, 0, stream>>>(ZC, w_deW1, de_b1, U, NCUST);
  k_gemm64<false><<<Gp, B, 0, stream>>>(ZP, w_deW1 + 64, nullptr, V, NPROD);
  // edge scoring
  k_edge<<<dim3((ELB + 255) / 256), B, 0, stream>>>(U, V, eli, de_W2, de_b2, (float*)d_out);
}

// Round 9
// 596.507 us; speedup vs baseline: 1.1885x; 1.1885x over previous
//
#include <hip/hip_runtime.h>
#include <hip/hip_bf16.h>

#define HID   128
#define OUTD  64
#define NPROD 100000
#define NCUST 50000
#define EPP   800000
#define EPC   800000
#define ELB   400000
#define BCAP  2048
#define RCAP  256      // per-replica capacity (2x headroom over ~128 mean)
#define CPAD  800      // counter stride (buckets) per replica bank

typedef __bf16 bf16x8 __attribute__((ext_vector_type(8)));
typedef float  f32x4  __attribute__((ext_vector_type(4)));
typedef unsigned short u16;
typedef unsigned int u32;

__device__ __forceinline__ float b2f(u16 u) {
  unsigned int v = ((unsigned int)u) << 16;
  float f; __builtin_memcpy(&f, &v, 4); return f;
}
__device__ __forceinline__ u16 f2b(float f) {
  __hip_bfloat16 h = __float2bfloat16(f);
  u16 u; __builtin_memcpy(&u, &h, 2); return u;
}

union Pack8 { u16 u[8]; int4 v; };

// XOR-swizzled LDS index for 128-col rows (16B chunks, swizzle by row&15).
__device__ __forceinline__ int sidx(int row, int chunk) {
  return row * HID + ((chunk ^ (row & 15)) << 3);
}
// Same for 64-col rows (8 chunks, swizzle by row&7).
__device__ __forceinline__ int sidx64(int row, int chunk) {
  return row * 64 + ((chunk ^ (row & 7)) << 3);
}

// ---------------- fp32 -> bf16 cast ----------------
__global__ __launch_bounds__(256) void k_cast(const float* __restrict__ src,
                                              u16* __restrict__ dst, int n8) {
  int i = blockIdx.x * 256 + threadIdx.x;
  if (i >= n8) return;
  float4 a = ((const float4*)src)[2 * i];
  float4 b = ((const float4*)src)[2 * i + 1];
  Pack8 p;
  p.u[0] = f2b(a.x); p.u[1] = f2b(a.y); p.u[2] = f2b(a.z); p.u[3] = f2b(a.w);
  p.u[4] = f2b(b.x); p.u[5] = f2b(b.y); p.u[6] = f2b(b.z); p.u[7] = f2b(b.w);
  ((int4*)dst)[i] = p.v;
}

#define NJOBS 13
struct CastJobs { const float* src[NJOBS]; int n8[NJOBS]; };

__global__ __launch_bounds__(256) void k_cast_w(CastJobs jobs, u16* __restrict__ wbuf) {
  int job = blockIdx.x >> 3;
  int idx = (blockIdx.x & 7) * 256 + threadIdx.x;
  int off8 = (job < 10) ? job * 2048 : 10 * 2048 + (job - 10) * 1024;
  if (idx >= jobs.n8[job]) return;
  const float* s = jobs.src[job];
  float4 a = ((const float4*)s)[2 * idx];
  float4 b = ((const float4*)s)[2 * idx + 1];
  Pack8 p;
  p.u[0] = f2b(a.x); p.u[1] = f2b(a.y); p.u[2] = f2b(a.z); p.u[3] = f2b(a.w);
  p.u[4] = f2b(b.x); p.u[5] = f2b(b.y); p.u[6] = f2b(b.z); p.u[7] = f2b(b.w);
  ((int4*)wbuf)[off8 + idx] = p.v;
}

// ---------------- CSR build: combined bucket scatter, XCD-replicated ----------
__global__ __launch_bounds__(256) void k_bucket2(const int* __restrict__ ei_pp,
                                                 const int* __restrict__ ei_pc,
                                                 int* __restrict__ bfill_pp,
                                                 int* __restrict__ bfill_pc,
                                                 u32* __restrict__ bss_pp,
                                                 u32* __restrict__ bss_pc) {
  int gb = blockIdx.x;
  int xcc;
  asm("s_getreg_b32 %0, hwreg(HW_REG_XCC_ID)" : "=s"(xcc));
  int rep = xcc & 7;
  if (gb < EPP / 256) {
    int e = gb * 256 + threadIdx.x;
    int d = ei_pp[EPP + e];
    int b = d >> 7;
    int p = atomicAdd(&bfill_pp[(rep * CPAD + b) << 4], 1);
    if (p < RCAP)
      bss_pp[(b << 11) + (rep << 8) + p] = ((u32)ei_pp[e] << 7) | (u32)(d & 127);
  } else {
    int e = (gb - EPP / 256) * 256 + threadIdx.x;
    int d = ei_pc[EPC + e];
    int b = d >> 6;
    int p = atomicAdd(&bfill_pc[(rep * CPAD + b) << 4], 1);
    if (p < RCAP)
      bss_pc[(b << 11) + (rep << 8) + p] = ((u32)ei_pc[e] << 7) | (u32)(d & 127);
  }
}

template <int K>
__global__ __launch_bounds__(256) void k_bsort(const u32* __restrict__ bss,
                                               const int* __restrict__ bfill,
                                               int* __restrict__ gctr,
                                               int* __restrict__ esrc,
                                               int* __restrict__ start,
                                               int* __restrict__ cnt,
                                               int n_nodes) {
  __shared__ u32 pairs[BCAP];
  __shared__ int outsrc[BCAP];
  __shared__ int lcnt[K], lstart[K], lfill[K];
  __shared__ int sh_n, sh_base, rn[8], roff[8];
  const int b = blockIdx.x, tid = threadIdx.x;
  if (tid < 8) rn[tid] = min(bfill[(tid * CPAD + b) << 4], RCAP);
  for (int j = tid; j < K; j += 256) { lcnt[j] = 0; lfill[j] = 0; }
  __syncthreads();
  if (tid == 0) {
    int run = 0;
    for (int r = 0; r < 8; ++r) { roff[r] = run; run += rn[r]; }
    sh_n = run;
    sh_base = atomicAdd(gctr, run);
  }
  __syncthreads();
  const int n = sh_n, base = sh_base;
  #pragma unroll
  for (int r = 0; r < 8; ++r) {
    int m = rn[r], o = roff[r];
    for (int i = tid; i < m; i += 256) {
      u32 p = bss[(b << 11) + (r << 8) + i];
      pairs[o + i] = p;
      atomicAdd(&lcnt[p & (K - 1)], 1);
    }
  }
  __syncthreads();
  if (tid == 0) {
    int run = 0;
    for (int j = 0; j < K; ++j) { lstart[j] = run; run += lcnt[j]; }
  }
  __syncthreads();
  for (int i = tid; i < n; i += 256) {
    u32 p = pairs[i];
    int ln = p & (K - 1);
    int pos = lstart[ln] + atomicAdd(&lfill[ln], 1);
    outsrc[pos] = (int)(p >> 7);
  }
  __syncthreads();
  for (int i = tid; i < n; i += 256) esrc[base + i] = outsrc[i];
  const int nb0 = b * K;
  for (int j = tid; j < K; j += 256) {
    int g = nb0 + j;
    if (g < n_nodes) { start[g] = base + lstart[j]; cnt[g] = lcnt[j]; }
  }
}

// ---------------- standalone mean aggregation (quarter-wave per node) --------
__global__ __launch_bounds__(256) void k_agg(const int* __restrict__ esrc,
                                             const int* __restrict__ start,
                                             const int* __restrict__ cnt,
                                             const u16* __restrict__ x,
                                             u16* __restrict__ outm, int n_dst) {
  int node = blockIdx.x * 16 + (threadIdx.x >> 4);
  int l16  = threadIdx.x & 15;
  if (node >= n_dst) return;
  int s0 = start[node], c = cnt[node];
  float acc[8] = {0.f, 0.f, 0.f, 0.f, 0.f, 0.f, 0.f, 0.f};
  for (int j0 = 0; j0 < c; j0 += 16) {
    int nch = min(16, c - j0);
    int eid = (l16 < nch) ? esrc[s0 + j0 + l16] : 0;
    for (int k = 0; k < nch; ++k) {
      int s = __shfl(eid, (threadIdx.x & 48) + k, 64);
      Pack8 p;
      p.v = *(const int4*)(x + (size_t)s * HID + l16 * 8);
      #pragma unroll
      for (int t = 0; t < 8; ++t) acc[t] += b2f(p.u[t]);
    }
  }
  float inv = 1.0f / (float)max(c, 1);
  Pack8 o;
  #pragma unroll
  for (int t = 0; t < 8; ++t) o.u[t] = f2b(acc[t] * inv);
  *(int4*)(outm + (size_t)node * HID + l16 * 8) = o.v;
}

// ---------------- dual-K GEMM (BN=128), optional dense epilogue chain --------
// Base: T = act(A1@W1^T + A2@W2^T + bias) [64 x 128 tile per block].
// CHAIN: instead of storing T, compute Z = T@Wlin^T + blin (64 cols), then
// out = Z @ dW1^T (+db1) and store only the final 64-col result. All chain
// steps are dense MFMA on LDS tiles (no gather -> no R8-style latency hazard).
template <bool RELU, bool A2F, bool CHAIN, bool CHB>
__global__ __launch_bounds__(256) void k_gemm(const u16* __restrict__ A1,
                                              const u16* __restrict__ W1,
                                              const void* __restrict__ A2v,
                                              const u16* __restrict__ W2,
                                              const float* __restrict__ bias,
                                              u16* __restrict__ out, int M,
                                              const u16* __restrict__ Wlin,
                                              const float* __restrict__ blin,
                                              const u16* __restrict__ dW1,
                                              const float* __restrict__ db1) {
  __shared__ __align__(16) u16 sA[64 * HID];
  __shared__ __align__(16) u16 sW[128 * HID];
  const int tid  = threadIdx.x;
  const int lane = tid & 63;
  const int wave = tid >> 6;
  const int q    = lane >> 4;
  const int r16  = lane & 15;
  const int m0   = blockIdx.x * 64;

  f32x4 acc[4][2];
  #pragma unroll
  for (int i = 0; i < 4; ++i)
    #pragma unroll
    for (int j = 0; j < 2; ++j) {
      acc[i][j][0] = 0.f; acc[i][j][1] = 0.f; acc[i][j][2] = 0.f; acc[i][j][3] = 0.f;
    }

  #pragma unroll
  for (int phase = 0; phase < 2; ++phase) {
    const u16* W = phase ? W2 : W1;
    if (phase) __syncthreads();
    #pragma unroll
    for (int i = 0; i < 4; ++i) {
      int idx = i * 256 + tid;
      int rr = idx >> 4, c8 = idx & 15;
      int gr = m0 + rr;
      Pack8 p; p.v = make_int4(0, 0, 0, 0);
      if (gr < M) {
        if (phase == 0 || !A2F) {
          const u16* A = phase ? (const u16*)A2v : A1;
          p.v = *(const int4*)(A + (size_t)gr * HID + c8 * 8);
        } else {
          const float* A = (const float*)A2v;
          const float* s = A + (size_t)gr * HID + c8 * 8;
          float4 f0 = ((const float4*)s)[0], f1 = ((const float4*)s)[1];
          p.u[0] = f2b(f0.x); p.u[1] = f2b(f0.y); p.u[2] = f2b(f0.z); p.u[3] = f2b(f0.w);
          p.u[4] = f2b(f1.x); p.u[5] = f2b(f1.y); p.u[6] = f2b(f1.z); p.u[7] = f2b(f1.w);
        }
      }
      *(int4*)(sA + sidx(rr, c8)) = p.v;
    }
    #pragma unroll
    for (int i = 0; i < 8; ++i) {
      int idx = i * 256 + tid;
      int rr = idx >> 4, c8 = idx & 15;
      *(int4*)(sW + sidx(rr, c8)) = *(const int4*)(W + (size_t)rr * HID + c8 * 8);
    }
    __syncthreads();
    #pragma unroll
    for (int ks = 0; ks < 4; ++ks) {
      int chunk = ks * 4 + q;
      bf16x8 a[4], b[2];
      #pragma unroll
      for (int mi = 0; mi < 4; ++mi)
        a[mi] = *(const bf16x8*)(sA + sidx(mi * 16 + r16, chunk));
      #pragma unroll
      for (int ni = 0; ni < 2; ++ni)
        b[ni] = *(const bf16x8*)(sW + sidx(wave * 32 + ni * 16 + r16, chunk));
      #pragma unroll
      for (int mi = 0; mi < 4; ++mi)
        #pragma unroll
        for (int ni = 0; ni < 2; ++ni)
          acc[mi][ni] = __builtin_amdgcn_mfma_f32_16x16x32_bf16(a[mi], b[ni], acc[mi][ni], 0, 0, 0);
    }
  }

  if (!CHAIN) {
    #pragma unroll
    for (int ni = 0; ni < 2; ++ni) {
      int col = wave * 32 + ni * 16 + r16;
      float bv = bias[col];
      #pragma unroll
      for (int mi = 0; mi < 4; ++mi)
        #pragma unroll
        for (int r = 0; r < 4; ++r) {
          int gr = m0 + mi * 16 + q * 4 + r;
          if (gr < M) {
            float v = acc[mi][ni][r] + bv;
            if (RELU) v = fmaxf(v, 0.f);
            out[(size_t)gr * HID + col] = f2b(v);
          }
        }
    }
    return;
  }

  // ---- chain epilogue ----
  // E1: T tile (relu+bias, bf16) -> sA (swizzled)
  __syncthreads();
  #pragma unroll
  for (int ni = 0; ni < 2; ++ni) {
    int col = wave * 32 + ni * 16 + r16;
    float bv = bias[col];
    #pragma unroll
    for (int mi = 0; mi < 4; ++mi)
      #pragma unroll
      for (int r = 0; r < 4; ++r) {
        int rl = mi * 16 + q * 4 + r;
        float v = acc[mi][ni][r] + bv;
        if (RELU) v = fmaxf(v, 0.f);
        sA[rl * HID + (((col >> 3) ^ (rl & 15)) << 3) + (col & 7)] = f2b(v);
      }
  }
  // E2: stage Wlin (64x128) at sW[0..8192], dW1 (64x64, row stride 128) at sW[8192..]
  #pragma unroll
  for (int i = 0; i < 4; ++i) {
    int idx = i * 256 + tid;
    int rr = idx >> 4, c8 = idx & 15;
    *(int4*)(sW + sidx(rr, c8)) = *(const int4*)(Wlin + (size_t)rr * HID + c8 * 8);
  }
  #pragma unroll
  for (int i = 0; i < 2; ++i) {
    int idx = i * 256 + tid;
    int rr = idx >> 3, c8 = idx & 7;
    *(int4*)(sW + 8192 + sidx64(rr, c8)) = *(const int4*)(dW1 + (size_t)rr * HID + c8 * 8);
  }
  __syncthreads();
  // E3: Z = T @ Wlin^T (K=128), wave covers cols wave*16+r16
  f32x4 az[4];
  #pragma unroll
  for (int i = 0; i < 4; ++i) { az[i][0]=0.f; az[i][1]=0.f; az[i][2]=0.f; az[i][3]=0.f; }
  #pragma unroll
  for (int ks = 0; ks < 4; ++ks) {
    int chunk = ks * 4 + q;
    bf16x8 b = *(const bf16x8*)(sW + sidx(wave * 16 + r16, chunk));
    #pragma unroll
    for (int mi = 0; mi < 4; ++mi) {
      bf16x8 a = *(const bf16x8*)(sA + sidx(mi * 16 + r16, chunk));
      az[mi] = __builtin_amdgcn_mfma_f32_16x16x32_bf16(a, b, az[mi], 0, 0, 0);
    }
  }
  // E4: Z + blin -> bf16 -> sZ at sW[12288..] (64x64 swizzled)
  {
    int col = wave * 16 + r16;
    float bl = blin[col];
    #pragma unroll
    for (int mi = 0; mi < 4; ++mi)
      #pragma unroll
      for (int r = 0; r < 4; ++r) {
        int rl = mi * 16 + q * 4 + r;
        sW[12288 + rl * 64 + (((col >> 3) ^ (rl & 7)) << 3) + (col & 7)] = f2b(az[mi][r] + bl);
      }
  }
  __syncthreads();
  // E5: out = Z @ dW1^T (K=64)
  f32x4 au[4];
  #pragma unroll
  for (int i = 0; i < 4; ++i) { au[i][0]=0.f; au[i][1]=0.f; au[i][2]=0.f; au[i][3]=0.f; }
  #pragma unroll
  for (int ks = 0; ks < 2; ++ks) {
    int chunk = ks * 4 + q;
    bf16x8 b = *(const bf16x8*)(sW + 8192 + sidx64(wave * 16 + r16, chunk));
    #pragma unroll
    for (int mi = 0; mi < 4; ++mi) {
      bf16x8 a = *(const bf16x8*)(sW + 12288 + sidx64(mi * 16 + r16, chunk));
      au[mi] = __builtin_amdgcn_mfma_f32_16x16x32_bf16(a, b, au[mi], 0, 0, 0);
    }
  }
  // E6: store final 64-col result (+db1 if CHB)
  {
    int col = wave * 16 + r16;
    float db = CHB ? db1[col] : 0.f;
    #pragma unroll
    for (int mi = 0; mi < 4; ++mi)
      #pragma unroll
      for (int r = 0; r < 4; ++r) {
        int gr = m0 + mi * 16 + q * 4 + r;
        if (gr < M) out[(size_t)gr * 64 + col] = f2b(au[mi][r] + db);
      }
  }
}

// ---------------- edge scorer: out[e] = w2 . relu(U[row]+V[col]) + b2 ---------
__global__ __launch_bounds__(256) void k_edge(const u16* __restrict__ U,
                                              const u16* __restrict__ V,
                                              const int* __restrict__ eli,
                                              const float* __restrict__ w2,
                                              const float* __restrict__ b2,
                                              float* __restrict__ out) {
  const int lane = threadIdx.x & 63;
  const int wave = threadIdx.x >> 6;
  const int se   = (lane >> 3);
  const int ch   = lane & 7;
  float w2c[8];
  #pragma unroll
  for (int j = 0; j < 8; ++j) w2c[j] = w2[ch * 8 + j];
  const float b2v = b2[0];
  const int e0 = blockIdx.x * 256;
  #pragma unroll
  for (int p = 0; p < 8; ++p) {
    int e = e0 + p * 32 + wave * 8 + se;
    if (e < ELB) {
      int r = eli[e];
      int c = eli[ELB + e];
      Pack8 pu, pv;
      pu.v = *(const int4*)(U + (size_t)r * 64 + ch * 8);
      pv.v = *(const int4*)(V + (size_t)c * 64 + ch * 8);
      float s = 0.f;
      #pragma unroll
      for (int j = 0; j < 8; ++j)
        s += fmaxf(b2f(pu.u[j]) + b2f(pv.u[j]), 0.f) * w2c[j];
      s += __shfl_xor(s, 1, 64);
      s += __shfl_xor(s, 2, 64);
      s += __shfl_xor(s, 4, 64);
      if (ch == 0) out[e] = s + b2v;
    }
  }
}

extern "C" void kernel_launch(void* const* d_in, const int* in_sizes, int n_in,
                              void* d_out, int out_size, void* d_ws, size_t ws_size,
                              hipStream_t stream) {
  const float* x_prod = (const float*)d_in[0];
  const float* x_cust = (const float*)d_in[1];
  const int* ei_pp    = (const int*)d_in[2];
  const int* ei_pc    = (const int*)d_in[3];
  const int* eli      = (const int*)d_in[4];

  const float *it_W1l, *it_W1r, *it_b1, *it_W2l, *it_W2r, *it_b2, *it_Wlin, *it_blin;
  const float *us_W1l, *us_W1r, *us_b1, *us_W2l, *us_W2r, *us_b2;
  const float *us_W3l, *us_W3r, *us_b3, *us_Wlin, *us_blin;
  if (in_sizes[6] == 128) {   // signature order (Wl, b, Wr)
    it_W1l  = (const float*)d_in[5];  it_b1   = (const float*)d_in[6];  it_W1r  = (const float*)d_in[7];
    it_W2l  = (const float*)d_in[8];  it_b2   = (const float*)d_in[9];  it_W2r  = (const float*)d_in[10];
    it_Wlin = (const float*)d_in[11]; it_blin = (const float*)d_in[12];
    us_W1l  = (const float*)d_in[13]; us_b1   = (const float*)d_in[14]; us_W1r  = (const float*)d_in[15];
    us_W2l  = (const float*)d_in[16]; us_b2   = (const float*)d_in[17]; us_W2r  = (const float*)d_in[18];
    us_W3l  = (const float*)d_in[19]; us_b3   = (const float*)d_in[20]; us_W3r  = (const float*)d_in[21];
    us_Wlin = (const float*)d_in[22]; us_blin = (const float*)d_in[23];
  } else {                    // setup_inputs dict order (Wl, Wr, b)
    it_W1l  = (const float*)d_in[5];  it_W1r  = (const float*)d_in[6];  it_b1   = (const float*)d_in[7];
    it_W2l  = (const float*)d_in[8];  it_W2r  = (const float*)d_in[9];  it_b2   = (const float*)d_in[10];
    it_Wlin = (const float*)d_in[11]; it_blin = (const float*)d_in[12];
    us_W1l  = (const float*)d_in[13]; us_W1r  = (const float*)d_in[14]; us_b1   = (const float*)d_in[15];
    us_W2l  = (const float*)d_in[16]; us_W2r  = (const float*)d_in[17]; us_b2   = (const float*)d_in[18];
    us_W3l  = (const float*)d_in[19]; us_W3r  = (const float*)d_in[20]; us_b3   = (const float*)d_in[21];
    us_Wlin = (const float*)d_in[22]; us_blin = (const float*)d_in[23];
  }
  const float* de_W1 = (const float*)d_in[24];
  const float* de_b1 = (const float*)d_in[25];
  const float* de_W2 = (const float*)d_in[26];
  const float* de_b2 = (const float*)d_in[27];

  const int NB_PP = (NPROD + 127) / 128;   // 782
  const int NB_PC = (NCUST + 63) / 64;     // 782

  char* ws = (char*)d_ws;
  int* bfill_pp = (int*)(ws + 0);              // 409600 B (line-padded)
  int* bfill_pc = (int*)(ws + 409600);         // 409600 B
  int* gctr     = (int*)(ws + 819200);         // 8 B (memset 0..819208)
  int* start_pp = (int*)(ws + 819264);
  int* cnt_pp   = (int*)(ws + 1219264);
  int* start_pc = (int*)(ws + 1619264);
  int* cnt_pc   = (int*)(ws + 1819264);
  int* esrc_pp  = (int*)(ws + 2019264);        // 3.2 MB \ U overlays both after
  int* esrc_pc  = (int*)(ws + 5219264);        // 3.2 MB /  aggs are done (6.4 MB)
  u16* wbuf  = (u16*)(ws + 8419264);           // 376832 B
  u16* XPB   = (u16*)(ws + 8796096);           // 25.6 MB: bf16 x_prod -> PX (in place)
  u16* meanb = (u16*)(ws + 34396096);          // 25.6 MB: mean_pp1 -> mean_pp2
  u16* P1    = (u16*)(ws + 59996096);          // 25.6 MB: bss -> p1
  u16* meanc = (u16*)(ws + 85596096);          // 12.8 MB: mean_pc1 -> mean_pc2
  u16* CX    = (u16*)(ws + 98396096);          // 12.8 MB: cx -> V  (peak 111.2 MB)
  u32* bss_pp = (u32*)P1;                      // 6.4 MB
  u32* bss_pc = (u32*)(ws + 59996096 + 6553600);
  u16* PX = XPB;
  u16* U  = (u16*)esrc_pp;                     // 50000*64*2 = 6.4 MB exact
  u16* V  = CX;                                // 100000*64*2 = 12.8 MB exact

  u16* w_it1l = wbuf + 0 * 16384;  u16* w_it1r = wbuf + 1 * 16384;
  u16* w_it2l = wbuf + 2 * 16384;  u16* w_it2r = wbuf + 3 * 16384;
  u16* w_us1l = wbuf + 4 * 16384;  u16* w_us1r = wbuf + 5 * 16384;
  u16* w_us2l = wbuf + 6 * 16384;  u16* w_us2r = wbuf + 7 * 16384;
  u16* w_us3l = wbuf + 8 * 16384;  u16* w_us3r = wbuf + 9 * 16384;
  u16* w_itlin = wbuf + 10 * 16384;
  u16* w_uslin = wbuf + 10 * 16384 + 8192;
  u16* w_deW1  = wbuf + 10 * 16384 + 2 * 8192;

  (void)n_in; (void)out_size; (void)ws_size;

  hipMemsetAsync(d_ws, 0, 819208, stream);

  dim3 B(256);
  k_cast<<<dim3((NPROD * HID / 8 + 255) / 256), B, 0, stream>>>(x_prod, XPB, NPROD * HID / 8);
  CastJobs jobs;
  jobs.src[0] = it_W1l;  jobs.src[1] = it_W1r;  jobs.src[2] = it_W2l;  jobs.src[3] = it_W2r;
  jobs.src[4] = us_W1l;  jobs.src[5] = us_W1r;  jobs.src[6] = us_W2l;  jobs.src[7] = us_W2r;
  jobs.src[8] = us_W3l;  jobs.src[9] = us_W3r;
  jobs.src[10] = it_Wlin; jobs.src[11] = us_Wlin; jobs.src[12] = de_W1;
  for (int i = 0; i < 10; ++i) jobs.n8[i] = 2048;
  for (int i = 10; i < 13; ++i) jobs.n8[i] = 1024;
  k_cast_w<<<dim3(NJOBS * 8), B, 0, stream>>>(jobs, wbuf);

  // CSR build
  k_bucket2<<<dim3(EPP / 256 + EPC / 256), B, 0, stream>>>(ei_pp, ei_pc, bfill_pp, bfill_pc,
                                                           bss_pp, bss_pc);
  k_bsort<128><<<dim3(NB_PP), B, 0, stream>>>(bss_pp, bfill_pp, gctr, esrc_pp, start_pp, cnt_pp, NPROD);
  k_bsort<64><<<dim3(NB_PC), B, 0, stream>>>(bss_pc, bfill_pc, gctr + 1, esrc_pc, start_pc, cnt_pc, NCUST);

  dim3 Gp((NPROD + 63) / 64), Gc((NCUST + 63) / 64);
  dim3 App((NPROD + 15) / 16), Apc((NCUST + 15) / 16);

  // layer-1 means from bf16 x_prod
  k_agg<<<App, B, 0, stream>>>(esrc_pp, start_pp, cnt_pp, XPB, meanb, NPROD);
  k_agg<<<Apc, B, 0, stream>>>(esrc_pc, start_pc, cnt_pc, XPB, meanc, NCUST);
  // cx = relu(mean_pc1@W2l + x_cust@W2r + b2)
  k_gemm<true, true, false, false><<<Gc, B, 0, stream>>>(
      meanc, w_us2l, x_cust, w_us2r, us_b2, CX, NCUST, nullptr, nullptr, nullptr, nullptr);
  // p1 / px from shared mean_pp1 (px in-place over XPB)
  k_gemm<true, false, false, false><<<Gp, B, 0, stream>>>(
      meanb, w_it1l, XPB, w_it1r, it_b1, P1, NPROD, nullptr, nullptr, nullptr, nullptr);
  k_gemm<true, false, false, false><<<Gp, B, 0, stream>>>(
      meanb, w_us1l, XPB, w_us1r, us_b1, PX, NPROD, nullptr, nullptr, nullptr, nullptr);
  // layer-2 means
  k_agg<<<App, B, 0, stream>>>(esrc_pp, start_pp, cnt_pp, P1, meanb, NPROD);
  k_agg<<<Apc, B, 0, stream>>>(esrc_pc, start_pc, cnt_pc, PX, meanc, NCUST);
  // us chain: cx2 -> z_cust -> U (over dead esrc region)
  k_gemm<true, false, true, true><<<Gc, B, 0, stream>>>(
      meanc, w_us3l, CX, w_us3r, us_b3, U, NCUST, w_uslin, us_blin, w_deW1, de_b1);
  // it chain: p2 -> z_prod -> V (over dead CX)
  k_gemm<true, false, true, false><<<Gp, B, 0, stream>>>(
      meanb, w_it2l, P1, w_it2r, it_b2, V, NPROD, w_itlin, it_blin, w_deW1 + 64, nullptr);
  // edge scoring
  k_edge<<<dim3((ELB + 255) / 256), B, 0, stream>>>(U, V, eli, de_W2, de_b2, (float*)d_out);
}

// Round 10
// 529.581 us; speedup vs baseline: 1.3387x; 1.1264x over previous
//
#include <hip/hip_runtime.h>
#include <hip/hip_bf16.h>

#define HID   128
#define OUTD  64
#define NPROD 100000
#define NCUST 50000
#define EPP   800000
#define EPC   800000
#define ELB   400000
#define NBK   391      // coarse buckets per graph (pp: K=256 nodes, pc: K=128)
#define EBLK  4096     // edges per bucket3 block
#define RCAP3 512      // slots per (bucket, replica); mean fill ~256
#define BCAP3 2560     // per-bucket LDS capacity in bsort (mean 2046, +11 sigma)
#define CPADN 400      // counter stride (buckets) per replica bank

typedef __bf16 bf16x8 __attribute__((ext_vector_type(8)));
typedef float  f32x4  __attribute__((ext_vector_type(4)));
typedef unsigned short u16;
typedef unsigned int u32;

__device__ __forceinline__ float b2f(u16 u) {
  unsigned int v = ((unsigned int)u) << 16;
  float f; __builtin_memcpy(&f, &v, 4); return f;
}
__device__ __forceinline__ u16 f2b(float f) {
  __hip_bfloat16 h = __float2bfloat16(f);
  u16 u; __builtin_memcpy(&u, &h, 2); return u;
}

union Pack8 { u16 u[8]; int4 v; };

// XOR-swizzled LDS index for 128-col rows (16B chunks, swizzle by row&15).
__device__ __forceinline__ int sidx(int row, int chunk) {
  return row * HID + ((chunk ^ (row & 15)) << 3);
}
// Same for 64-col rows (8 chunks, swizzle by row&7).
__device__ __forceinline__ int sidx64(int row, int chunk) {
  return row * 64 + ((chunk ^ (row & 7)) << 3);
}

// ---------------- fp32 -> bf16 cast ----------------
__global__ __launch_bounds__(256) void k_cast(const float* __restrict__ src,
                                              u16* __restrict__ dst, int n8) {
  int i = blockIdx.x * 256 + threadIdx.x;
  if (i >= n8) return;
  float4 a = ((const float4*)src)[2 * i];
  float4 b = ((const float4*)src)[2 * i + 1];
  Pack8 p;
  p.u[0] = f2b(a.x); p.u[1] = f2b(a.y); p.u[2] = f2b(a.z); p.u[3] = f2b(a.w);
  p.u[4] = f2b(b.x); p.u[5] = f2b(b.y); p.u[6] = f2b(b.z); p.u[7] = f2b(b.w);
  ((int4*)dst)[i] = p.v;
}

#define NJOBS 13
struct CastJobs { const float* src[NJOBS]; int n8[NJOBS]; };

__global__ __launch_bounds__(256) void k_cast_w(CastJobs jobs, u16* __restrict__ wbuf) {
  int job = blockIdx.x >> 3;
  int idx = (blockIdx.x & 7) * 256 + threadIdx.x;
  int off8 = (job < 10) ? job * 2048 : 10 * 2048 + (job - 10) * 1024;
  if (idx >= jobs.n8[job]) return;
  const float* s = jobs.src[job];
  float4 a = ((const float4*)s)[2 * idx];
  float4 b = ((const float4*)s)[2 * idx + 1];
  Pack8 p;
  p.u[0] = f2b(a.x); p.u[1] = f2b(a.y); p.u[2] = f2b(a.z); p.u[3] = f2b(a.w);
  p.u[4] = f2b(b.x); p.u[5] = f2b(b.y); p.u[6] = f2b(b.z); p.u[7] = f2b(b.w);
  ((int4*)wbuf)[off8 + idx] = p.v;
}

// ---------------- CSR pass A: per-block LDS counting sort + batched scatter ----
// 4096 edges/block binned into 391 buckets in LDS; ONE global atomic per
// nonempty bucket reserves a run; runs written coalesced. Distinct-line global
// ops per block: ~1100 vs 8192 for per-edge scatter (R9's 70us bottleneck).
__global__ __launch_bounds__(256) void k_bucket3(const int* __restrict__ ei_pp,
                                                 const int* __restrict__ ei_pc,
                                                 int* __restrict__ bfill_pp,
                                                 int* __restrict__ bfill_pc,
                                                 u32* __restrict__ bss_pp,
                                                 u32* __restrict__ bss_pc) {
  __shared__ int lcnt[NBK], lstart[NBK], lfill[NBK], gbase[NBK];
  __shared__ u32 spay[EBLK];
  __shared__ u16 sbk[EBLK];
  __shared__ int wtot[4];
  const int t = threadIdx.x;
  const int lane = t & 63, wv = t >> 6;
  int xcc; asm("s_getreg_b32 %0, hwreg(HW_REG_XCC_ID)" : "=s"(xcc));
  const int rep = xcc & 7;
  const int NBLK_PP = (EPP + EBLK - 1) / EBLK;   // 196
  const bool isPP = (int)blockIdx.x < NBLK_PP;
  const int* ei = isPP ? ei_pp : ei_pc;
  const int E  = isPP ? EPP : EPC;
  const int SH = isPP ? 8 : 7;                   // K = 256 / 128 nodes per bucket
  int* bfill = isPP ? bfill_pp : bfill_pc;
  u32* bss   = isPP ? bss_pp : bss_pc;
  const int base = (isPP ? (int)blockIdx.x : (int)blockIdx.x - NBLK_PP) * EBLK;
  const int n = min(EBLK, E - base);

  for (int j = t; j < NBK; j += 256) { lcnt[j] = 0; lfill[j] = 0; }
  __syncthreads();

  u32 pay[16]; int bk[16];
  #pragma unroll
  for (int i = 0; i < 16; ++i) {
    int idx = i * 256 + t;
    bk[i] = -1;
    if (idx < n) {
      int e = base + idx;
      int s = ei[e];
      int d = ei[E + e];
      int b = d >> SH;
      bk[i] = b;
      pay[i] = ((u32)s << SH) | (u32)(d & ((1 << SH) - 1));
      atomicAdd(&lcnt[b], 1);
    }
  }
  __syncthreads();
  // parallel exclusive scan of lcnt (2 entries/thread, shfl wave scan)
  {
    int a0 = (2 * t < NBK) ? lcnt[2 * t] : 0;
    int a1 = (2 * t + 1 < NBK) ? lcnt[2 * t + 1] : 0;
    int s = a0 + a1;
    #pragma unroll
    for (int d = 1; d < 64; d <<= 1) {
      int u = __shfl_up(s, d, 64);
      if (lane >= d) s += u;
    }
    if (lane == 63) wtot[wv] = s;
    __syncthreads();
    int wpre = 0;
    for (int w = 0; w < wv; ++w) wpre += wtot[w];
    int excl = s + wpre - (a0 + a1);
    if (2 * t < NBK) lstart[2 * t] = excl;
    if (2 * t + 1 < NBK) lstart[2 * t + 1] = excl + a0;
  }
  __syncthreads();
  // one global atomic per nonempty bucket reserves the run
  for (int b = t; b < NBK; b += 256) {
    int c = lcnt[b];
    gbase[b] = c ? atomicAdd(&bfill[(rep * CPADN + b) << 4], c) : 0;
  }
  // LDS scatter sorted by bucket
  #pragma unroll
  for (int i = 0; i < 16; ++i) {
    if (bk[i] >= 0) {
      int pos = lstart[bk[i]] + atomicAdd(&lfill[bk[i]], 1);
      spay[pos] = pay[i];
      sbk[pos] = (u16)bk[i];
    }
  }
  __syncthreads();
  // coalesced run writeout
  for (int i = t; i < n; i += 256) {
    int b = sbk[i];
    int slot = gbase[b] + (i - lstart[b]);
    if (slot < RCAP3)
      bss[(b * 8 + rep) * RCAP3 + slot] = spay[i];
  }
}

// ---------------- CSR pass B: per-bucket fine counting sort ----------------
template <int K, int SHL>
__global__ __launch_bounds__(256) void k_bsort(const u32* __restrict__ bss,
                                               const int* __restrict__ bfill,
                                               int* __restrict__ gctr,
                                               int* __restrict__ esrc,
                                               int* __restrict__ start,
                                               int* __restrict__ cnt,
                                               int n_nodes) {
  __shared__ u32 pairs[BCAP3];
  __shared__ int outsrc[BCAP3];
  __shared__ int lcnt[K], lstart[K], lfill[K];
  __shared__ int sh_n, sh_base, rn[8], roff[8];
  const int b = blockIdx.x, tid = threadIdx.x;
  if (tid < 8) rn[tid] = min(bfill[(tid * CPADN + b) << 4], RCAP3);
  for (int j = tid; j < K; j += 256) { lcnt[j] = 0; lfill[j] = 0; }
  __syncthreads();
  if (tid == 0) {
    int run = 0;
    for (int r = 0; r < 8; ++r) {
      roff[r] = run;
      int m = min(rn[r], BCAP3 - run);
      rn[r] = m;
      run += m;
    }
    sh_n = run;
    sh_base = atomicAdd(gctr, run);
  }
  __syncthreads();
  const int n = sh_n, base = sh_base;
  #pragma unroll
  for (int r = 0; r < 8; ++r) {
    int m = rn[r], o = roff[r];
    for (int i = tid; i < m; i += 256) {
      u32 p = bss[(b * 8 + r) * RCAP3 + i];
      pairs[o + i] = p;
      atomicAdd(&lcnt[p & (K - 1)], 1);
    }
  }
  __syncthreads();
  if (tid == 0) {
    int run = 0;
    for (int j = 0; j < K; ++j) { lstart[j] = run; run += lcnt[j]; }
  }
  __syncthreads();
  for (int i = tid; i < n; i += 256) {
    u32 p = pairs[i];
    int ln = p & (K - 1);
    int pos = lstart[ln] + atomicAdd(&lfill[ln], 1);
    outsrc[pos] = (int)(p >> SHL);
  }
  __syncthreads();
  for (int i = tid; i < n; i += 256) esrc[base + i] = outsrc[i];
  const int nb0 = b * K;
  for (int j = tid; j < K; j += 256) {
    int g = nb0 + j;
    if (g < n_nodes) { start[g] = base + lstart[j]; cnt[g] = lcnt[j]; }
  }
}

// ---------------- combined mean aggregation (quarter-wave per node, x4 MLP) ----
__global__ __launch_bounds__(256) void k_agg2(const int* __restrict__ es_a,
                                              const int* __restrict__ st_a,
                                              const int* __restrict__ cn_a,
                                              const u16* __restrict__ xa,
                                              u16* __restrict__ oa, int na,
                                              const int* __restrict__ es_b,
                                              const int* __restrict__ st_b,
                                              const int* __restrict__ cn_b,
                                              const u16* __restrict__ xb,
                                              u16* __restrict__ ob, int nb, int blkA) {
  const int t = threadIdx.x;
  const bool A = (int)blockIdx.x < blkA;
  const int node = (A ? (int)blockIdx.x : (int)blockIdx.x - blkA) * 16 + (t >> 4);
  const int l16 = t & 15;
  const int q4  = t & 48;
  if (node >= (A ? na : nb)) return;
  const int* esrc  = A ? es_a : es_b;
  const u16* x     = A ? xa : xb;
  u16* outm        = A ? oa : ob;
  int s0 = (A ? st_a : st_b)[node];
  int c  = (A ? cn_a : cn_b)[node];
  float acc[8] = {0.f, 0.f, 0.f, 0.f, 0.f, 0.f, 0.f, 0.f};
  for (int j0 = 0; j0 < c; j0 += 16) {
    int nch = min(16, c - j0);
    int eid = (l16 < nch) ? esrc[s0 + j0 + l16] : 0;
    int k = 0;
    for (; k + 4 <= nch; k += 4) {   // 4 independent loads in flight
      int s0i = __shfl(eid, q4 + k, 64);
      int s1i = __shfl(eid, q4 + k + 1, 64);
      int s2i = __shfl(eid, q4 + k + 2, 64);
      int s3i = __shfl(eid, q4 + k + 3, 64);
      Pack8 p0, p1, p2, p3;
      p0.v = *(const int4*)(x + (size_t)s0i * HID + l16 * 8);
      p1.v = *(const int4*)(x + (size_t)s1i * HID + l16 * 8);
      p2.v = *(const int4*)(x + (size_t)s2i * HID + l16 * 8);
      p3.v = *(const int4*)(x + (size_t)s3i * HID + l16 * 8);
      #pragma unroll
      for (int u = 0; u < 8; ++u)
        acc[u] += (b2f(p0.u[u]) + b2f(p1.u[u])) + (b2f(p2.u[u]) + b2f(p3.u[u]));
    }
    for (; k < nch; ++k) {
      int s = __shfl(eid, q4 + k, 64);
      Pack8 p;
      p.v = *(const int4*)(x + (size_t)s * HID + l16 * 8);
      #pragma unroll
      for (int u = 0; u < 8; ++u) acc[u] += b2f(p.u[u]);
    }
  }
  float inv = 1.0f / (float)max(c, 1);
  Pack8 o;
  #pragma unroll
  for (int u = 0; u < 8; ++u) o.u[u] = f2b(acc[u] * inv);
  *(int4*)(outm + (size_t)node * HID + l16 * 8) = o.v;
}

// ---------------- dual-K GEMM (BN=128), optional dense epilogue chain --------
template <bool RELU, bool A2F, bool CHAIN, bool CHB>
__global__ __launch_bounds__(256) void k_gemm(const u16* __restrict__ A1,
                                              const u16* __restrict__ W1,
                                              const void* __restrict__ A2v,
                                              const u16* __restrict__ W2,
                                              const float* __restrict__ bias,
                                              u16* __restrict__ out, int M,
                                              const u16* __restrict__ Wlin,
                                              const float* __restrict__ blin,
                                              const u16* __restrict__ dW1,
                                              const float* __restrict__ db1) {
  __shared__ __align__(16) u16 sA[64 * HID];
  __shared__ __align__(16) u16 sW[128 * HID];
  const int tid  = threadIdx.x;
  const int lane = tid & 63;
  const int wave = tid >> 6;
  const int q    = lane >> 4;
  const int r16  = lane & 15;
  const int m0   = blockIdx.x * 64;

  f32x4 acc[4][2];
  #pragma unroll
  for (int i = 0; i < 4; ++i)
    #pragma unroll
    for (int j = 0; j < 2; ++j) {
      acc[i][j][0] = 0.f; acc[i][j][1] = 0.f; acc[i][j][2] = 0.f; acc[i][j][3] = 0.f;
    }

  #pragma unroll
  for (int phase = 0; phase < 2; ++phase) {
    const u16* W = phase ? W2 : W1;
    if (phase) __syncthreads();
    #pragma unroll
    for (int i = 0; i < 4; ++i) {
      int idx = i * 256 + tid;
      int rr = idx >> 4, c8 = idx & 15;
      int gr = m0 + rr;
      Pack8 p; p.v = make_int4(0, 0, 0, 0);
      if (gr < M) {
        if (phase == 0 || !A2F) {
          const u16* A = phase ? (const u16*)A2v : A1;
          p.v = *(const int4*)(A + (size_t)gr * HID + c8 * 8);
        } else {
          const float* A = (const float*)A2v;
          const float* s = A + (size_t)gr * HID + c8 * 8;
          float4 f0 = ((const float4*)s)[0], f1 = ((const float4*)s)[1];
          p.u[0] = f2b(f0.x); p.u[1] = f2b(f0.y); p.u[2] = f2b(f0.z); p.u[3] = f2b(f0.w);
          p.u[4] = f2b(f1.x); p.u[5] = f2b(f1.y); p.u[6] = f2b(f1.z); p.u[7] = f2b(f1.w);
        }
      }
      *(int4*)(sA + sidx(rr, c8)) = p.v;
    }
    #pragma unroll
    for (int i = 0; i < 8; ++i) {
      int idx = i * 256 + tid;
      int rr = idx >> 4, c8 = idx & 15;
      *(int4*)(sW + sidx(rr, c8)) = *(const int4*)(W + (size_t)rr * HID + c8 * 8);
    }
    __syncthreads();
    #pragma unroll
    for (int ks = 0; ks < 4; ++ks) {
      int chunk = ks * 4 + q;
      bf16x8 a[4], b[2];
      #pragma unroll
      for (int mi = 0; mi < 4; ++mi)
        a[mi] = *(const bf16x8*)(sA + sidx(mi * 16 + r16, chunk));
      #pragma unroll
      for (int ni = 0; ni < 2; ++ni)
        b[ni] = *(const bf16x8*)(sW + sidx(wave * 32 + ni * 16 + r16, chunk));
      #pragma unroll
      for (int mi = 0; mi < 4; ++mi)
        #pragma unroll
        for (int ni = 0; ni < 2; ++ni)
          acc[mi][ni] = __builtin_amdgcn_mfma_f32_16x16x32_bf16(a[mi], b[ni], acc[mi][ni], 0, 0, 0);
    }
  }

  if (!CHAIN) {
    #pragma unroll
    for (int ni = 0; ni < 2; ++ni) {
      int col = wave * 32 + ni * 16 + r16;
      float bv = bias[col];
      #pragma unroll
      for (int mi = 0; mi < 4; ++mi)
        #pragma unroll
        for (int r = 0; r < 4; ++r) {
          int gr = m0 + mi * 16 + q * 4 + r;
          if (gr < M) {
            float v = acc[mi][ni][r] + bv;
            if (RELU) v = fmaxf(v, 0.f);
            out[(size_t)gr * HID + col] = f2b(v);
          }
        }
    }
    return;
  }

  // chain: T(relu) -> Z = T@Wlin^T + blin -> out = Z@dW1^T (+db1), all in LDS
  __syncthreads();
  #pragma unroll
  for (int ni = 0; ni < 2; ++ni) {
    int col = wave * 32 + ni * 16 + r16;
    float bv = bias[col];
    #pragma unroll
    for (int mi = 0; mi < 4; ++mi)
      #pragma unroll
      for (int r = 0; r < 4; ++r) {
        int rl = mi * 16 + q * 4 + r;
        float v = acc[mi][ni][r] + bv;
        if (RELU) v = fmaxf(v, 0.f);
        sA[rl * HID + (((col >> 3) ^ (rl & 15)) << 3) + (col & 7)] = f2b(v);
      }
  }
  #pragma unroll
  for (int i = 0; i < 4; ++i) {
    int idx = i * 256 + tid;
    int rr = idx >> 4, c8 = idx & 15;
    *(int4*)(sW + sidx(rr, c8)) = *(const int4*)(Wlin + (size_t)rr * HID + c8 * 8);
  }
  #pragma unroll
  for (int i = 0; i < 2; ++i) {
    int idx = i * 256 + tid;
    int rr = idx >> 3, c8 = idx & 7;
    *(int4*)(sW + 8192 + sidx64(rr, c8)) = *(const int4*)(dW1 + (size_t)rr * HID + c8 * 8);
  }
  __syncthreads();
  f32x4 az[4];
  #pragma unroll
  for (int i = 0; i < 4; ++i) { az[i][0]=0.f; az[i][1]=0.f; az[i][2]=0.f; az[i][3]=0.f; }
  #pragma unroll
  for (int ks = 0; ks < 4; ++ks) {
    int chunk = ks * 4 + q;
    bf16x8 b = *(const bf16x8*)(sW + sidx(wave * 16 + r16, chunk));
    #pragma unroll
    for (int mi = 0; mi < 4; ++mi) {
      bf16x8 a = *(const bf16x8*)(sA + sidx(mi * 16 + r16, chunk));
      az[mi] = __builtin_amdgcn_mfma_f32_16x16x32_bf16(a, b, az[mi], 0, 0, 0);
    }
  }
  {
    int col = wave * 16 + r16;
    float bl = blin[col];
    #pragma unroll
    for (int mi = 0; mi < 4; ++mi)
      #pragma unroll
      for (int r = 0; r < 4; ++r) {
        int rl = mi * 16 + q * 4 + r;
        sW[12288 + rl * 64 + (((col >> 3) ^ (rl & 7)) << 3) + (col & 7)] = f2b(az[mi][r] + bl);
      }
  }
  __syncthreads();
  f32x4 au[4];
  #pragma unroll
  for (int i = 0; i < 4; ++i) { au[i][0]=0.f; au[i][1]=0.f; au[i][2]=0.f; au[i][3]=0.f; }
  #pragma unroll
  for (int ks = 0; ks < 2; ++ks) {
    int chunk = ks * 4 + q;
    bf16x8 b = *(const bf16x8*)(sW + 8192 + sidx64(wave * 16 + r16, chunk));
    #pragma unroll
    for (int mi = 0; mi < 4; ++mi) {
      bf16x8 a = *(const bf16x8*)(sW + 12288 + sidx64(mi * 16 + r16, chunk));
      au[mi] = __builtin_amdgcn_mfma_f32_16x16x32_bf16(a, b, au[mi], 0, 0, 0);
    }
  }
  {
    int col = wave * 16 + r16;
    float db = CHB ? db1[col] : 0.f;
    #pragma unroll
    for (int mi = 0; mi < 4; ++mi)
      #pragma unroll
      for (int r = 0; r < 4; ++r) {
        int gr = m0 + mi * 16 + q * 4 + r;
        if (gr < M) out[(size_t)gr * 64 + col] = f2b(au[mi][r] + db);
      }
  }
}

// ---------------- edge scorer: out[e] = w2 . relu(U[row]+V[col]) + b2 ---------
__global__ __launch_bounds__(256) void k_edge(const u16* __restrict__ U,
                                              const u16* __restrict__ V,
                                              const int* __restrict__ eli,
                                              const float* __restrict__ w2,
                                              const float* __restrict__ b2,
                                              float* __restrict__ out) {
  const int lane = threadIdx.x & 63;
  const int wave = threadIdx.x >> 6;
  const int se   = (lane >> 3);
  const int ch   = lane & 7;
  float w2c[8];
  #pragma unroll
  for (int j = 0; j < 8; ++j) w2c[j] = w2[ch * 8 + j];
  const float b2v = b2[0];
  const int e0 = blockIdx.x * 256;
  #pragma unroll
  for (int p = 0; p < 8; ++p) {
    int e = e0 + p * 32 + wave * 8 + se;
    if (e < ELB) {
      int r = eli[e];
      int c = eli[ELB + e];
      Pack8 pu, pv;
      pu.v = *(const int4*)(U + (size_t)r * 64 + ch * 8);
      pv.v = *(const int4*)(V + (size_t)c * 64 + ch * 8);
      float s = 0.f;
      #pragma unroll
      for (int j = 0; j < 8; ++j)
        s += fmaxf(b2f(pu.u[j]) + b2f(pv.u[j]), 0.f) * w2c[j];
      s += __shfl_xor(s, 1, 64);
      s += __shfl_xor(s, 2, 64);
      s += __shfl_xor(s, 4, 64);
      if (ch == 0) out[e] = s + b2v;
    }
  }
}

extern "C" void kernel_launch(void* const* d_in, const int* in_sizes, int n_in,
                              void* d_out, int out_size, void* d_ws, size_t ws_size,
                              hipStream_t stream) {
  const float* x_prod = (const float*)d_in[0];
  const float* x_cust = (const float*)d_in[1];
  const int* ei_pp    = (const int*)d_in[2];
  const int* ei_pc    = (const int*)d_in[3];
  const int* eli      = (const int*)d_in[4];

  const float *it_W1l, *it_W1r, *it_b1, *it_W2l, *it_W2r, *it_b2, *it_Wlin, *it_blin;
  const float *us_W1l, *us_W1r, *us_b1, *us_W2l, *us_W2r, *us_b2;
  const float *us_W3l, *us_W3r, *us_b3, *us_Wlin, *us_blin;
  if (in_sizes[6] == 128) {   // signature order (Wl, b, Wr)
    it_W1l  = (const float*)d_in[5];  it_b1   = (const float*)d_in[6];  it_W1r  = (const float*)d_in[7];
    it_W2l  = (const float*)d_in[8];  it_b2   = (const float*)d_in[9];  it_W2r  = (const float*)d_in[10];
    it_Wlin = (const float*)d_in[11]; it_blin = (const float*)d_in[12];
    us_W1l  = (const float*)d_in[13]; us_b1   = (const float*)d_in[14]; us_W1r  = (const float*)d_in[15];
    us_W2l  = (const float*)d_in[16]; us_b2   = (const float*)d_in[17]; us_W2r  = (const float*)d_in[18];
    us_W3l  = (const float*)d_in[19]; us_b3   = (const float*)d_in[20]; us_W3r  = (const float*)d_in[21];
    us_Wlin = (const float*)d_in[22]; us_blin = (const float*)d_in[23];
  } else {                    // setup_inputs dict order (Wl, Wr, b)
    it_W1l  = (const float*)d_in[5];  it_W1r  = (const float*)d_in[6];  it_b1   = (const float*)d_in[7];
    it_W2l  = (const float*)d_in[8];  it_W2r  = (const float*)d_in[9];  it_b2   = (const float*)d_in[10];
    it_Wlin = (const float*)d_in[11]; it_blin = (const float*)d_in[12];
    us_W1l  = (const float*)d_in[13]; us_W1r  = (const float*)d_in[14]; us_b1   = (const float*)d_in[15];
    us_W2l  = (const float*)d_in[16]; us_W2r  = (const float*)d_in[17]; us_b2   = (const float*)d_in[18];
    us_W3l  = (const float*)d_in[19]; us_W3r  = (const float*)d_in[20]; us_b3   = (const float*)d_in[21];
    us_Wlin = (const float*)d_in[22]; us_blin = (const float*)d_in[23];
  }
  const float* de_W1 = (const float*)d_in[24];
  const float* de_b1 = (const float*)d_in[25];
  const float* de_W2 = (const float*)d_in[26];
  const float* de_b2 = (const float*)d_in[27];

  char* ws = (char*)d_ws;
  int* bfill_pp = (int*)(ws + 0);              // 8*400*16*4 = 204800 B used (line-padded)
  int* bfill_pc = (int*)(ws + 409600);
  int* gctr     = (int*)(ws + 819200);         // 8 B (memset 0..819208)
  int* start_pp = (int*)(ws + 819264);
  int* cnt_pp   = (int*)(ws + 1219264);
  int* start_pc = (int*)(ws + 1619264);
  int* cnt_pc   = (int*)(ws + 1819264);
  int* esrc_pp  = (int*)(ws + 2019264);        // 3.2 MB \ U overlays after layer-2 aggs
  int* esrc_pc  = (int*)(ws + 5219264);        // 3.2 MB /
  u16* wbuf  = (u16*)(ws + 8419264);           // 376832 B
  u16* XPB   = (u16*)(ws + 8796096);           // 25.6 MB: bf16 x_prod -> PX (in place)
  u16* meanb = (u16*)(ws + 34396096);          // 25.6 MB: mean_pp1 -> mean_pp2
  u16* P1    = (u16*)(ws + 59996096);          // 25.6 MB: bss -> p1
  u16* meanc = (u16*)(ws + 85596096);          // 12.8 MB: mean_pc1 -> mean_pc2
  u16* CX    = (u16*)(ws + 98396096);          // 12.8 MB: cx -> V (peak ~111.2 MB)
  u32* bss_pp = (u32*)P1;                      // 391*8*512*4 = 6.1 MB
  u32* bss_pc = (u32*)(ws + 59996096 + 6553600);
  u16* PX = XPB;
  u16* U  = (u16*)esrc_pp;                     // 50000*64*2 = 6.4 MB exact
  u16* V  = CX;                                // 100000*64*2 = 12.8 MB exact

  u16* w_it1l = wbuf + 0 * 16384;  u16* w_it1r = wbuf + 1 * 16384;
  u16* w_it2l = wbuf + 2 * 16384;  u16* w_it2r = wbuf + 3 * 16384;
  u16* w_us1l = wbuf + 4 * 16384;  u16* w_us1r = wbuf + 5 * 16384;
  u16* w_us2l = wbuf + 6 * 16384;  u16* w_us2r = wbuf + 7 * 16384;
  u16* w_us3l = wbuf + 8 * 16384;  u16* w_us3r = wbuf + 9 * 16384;
  u16* w_itlin = wbuf + 10 * 16384;
  u16* w_uslin = wbuf + 10 * 16384 + 8192;
  u16* w_deW1  = wbuf + 10 * 16384 + 2 * 8192;

  (void)n_in; (void)out_size; (void)ws_size;

  hipMemsetAsync(d_ws, 0, 819208, stream);

  dim3 B(256);
  k_cast<<<dim3((NPROD * HID / 8 + 255) / 256), B, 0, stream>>>(x_prod, XPB, NPROD * HID / 8);
  CastJobs jobs;
  jobs.src[0] = it_W1l;  jobs.src[1] = it_W1r;  jobs.src[2] = it_W2l;  jobs.src[3] = it_W2r;
  jobs.src[4] = us_W1l;  jobs.src[5] = us_W1r;  jobs.src[6] = us_W2l;  jobs.src[7] = us_W2r;
  jobs.src[8] = us_W3l;  jobs.src[9] = us_W3r;
  jobs.src[10] = it_Wlin; jobs.src[11] = us_Wlin; jobs.src[12] = de_W1;
  for (int i = 0; i < 10; ++i) jobs.n8[i] = 2048;
  for (int i = 10; i < 13; ++i) jobs.n8[i] = 1024;
  k_cast_w<<<dim3(NJOBS * 8), B, 0, stream>>>(jobs, wbuf);

  // CSR build
  const int NBLK_PP = (EPP + EBLK - 1) / EBLK;   // 196
  const int NBLK_PC = (EPC + EBLK - 1) / EBLK;   // 196
  k_bucket3<<<dim3(NBLK_PP + NBLK_PC), B, 0, stream>>>(ei_pp, ei_pc, bfill_pp, bfill_pc,
                                                       bss_pp, bss_pc);
  k_bsort<256, 8><<<dim3(NBK), B, 0, stream>>>(bss_pp, bfill_pp, gctr, esrc_pp, start_pp, cnt_pp, NPROD);
  k_bsort<128, 7><<<dim3(NBK), B, 0, stream>>>(bss_pc, bfill_pc, gctr + 1, esrc_pc, start_pc, cnt_pc, NCUST);

  dim3 Gp((NPROD + 63) / 64), Gc((NCUST + 63) / 64);
  const int App = (NPROD + 15) / 16, Apc = (NCUST + 15) / 16;

  // layer-1 means (pp + pc in one launch)
  k_agg2<<<dim3(App + Apc), B, 0, stream>>>(esrc_pp, start_pp, cnt_pp, XPB, meanb, NPROD,
                                            esrc_pc, start_pc, cnt_pc, XPB, meanc, NCUST, App);
  // cx = relu(mean_pc1@W2l + x_cust@W2r + b2)
  k_gemm<true, true, false, false><<<Gc, B, 0, stream>>>(
      meanc, w_us2l, x_cust, w_us2r, us_b2, CX, NCUST, nullptr, nullptr, nullptr, nullptr);
  // p1 / px from shared mean_pp1 (px in-place over XPB)
  k_gemm<true, false, false, false><<<Gp, B, 0, stream>>>(
      meanb, w_it1l, XPB, w_it1r, it_b1, P1, NPROD, nullptr, nullptr, nullptr, nullptr);
  k_gemm<true, false, false, false><<<Gp, B, 0, stream>>>(
      meanb, w_us1l, XPB, w_us1r, us_b1, PX, NPROD, nullptr, nullptr, nullptr, nullptr);
  // layer-2 means (pp from P1, pc from PX, one launch)
  k_agg2<<<dim3(App + Apc), B, 0, stream>>>(esrc_pp, start_pp, cnt_pp, P1, meanb, NPROD,
                                            esrc_pc, start_pc, cnt_pc, PX, meanc, NCUST, App);
  // us chain: cx2 -> z_cust -> U (over dead esrc region)
  k_gemm<true, false, true, true><<<Gc, B, 0, stream>>>(
      meanc, w_us3l, CX, w_us3r, us_b3, U, NCUST, w_uslin, us_blin, w_deW1, de_b1);
  // it chain: p2 -> z_prod -> V (over dead CX)
  k_gemm<true, false, true, false><<<Gp, B, 0, stream>>>(
      meanb, w_it2l, P1, w_it2r, it_b2, V, NPROD, w_itlin, it_blin, w_deW1 + 64, nullptr);
  // edge scoring
  k_edge<<<dim3((ELB + 255) / 256), B, 0, stream>>>(U, V, eli, de_W2, de_b2, (float*)d_out);
}